// Round 9
// baseline (42013.879 us; speedup 1.0000x reference)
//
#include <hip/hip_runtime.h>

#define T_STEPS 8192
#define F_IN 64
#define R_DIM 2048
#define G_BLK 256
#define ROWS_PER_BLK 8   // R_DIM / G_BLK
#define LR 0.9f
#define PKT_U64 8        // 64-B packet: ull[0..3] = 8 floats of x-slice, ull[4].lo32 = epoch

// Padded LDS index for x: +4 floats per 64 -> 16-B alignment kept, stride-272B
// fan-out on compute ds_read_b128 -> 4-way bank conflict (1.58x, acceptable).
__device__ __forceinline__ int xidx(int c) { return c + ((c >> 6) << 2); }

// tanh via v_exp_f32: 1 - 2/(e^{2y}+1). e=inf -> 1, e=0 -> -1 (no NaN), ~1e-6 rel err.
__device__ __forceinline__ float fast_tanh(float y) {
    float e = __expf(2.f * y);
    return 1.f - 2.f / (e + 1.f);
}

// ---------------- proj = u_in @ Win^T + b  (one-time, written into d_out) ----
__global__ __launch_bounds__(256) void esn_proj_kernel(
    const float* __restrict__ u, const float* __restrict__ Winw,
    const float* __restrict__ Winb, float* __restrict__ proj)
{
    __shared__ float u_s[64 * F_IN];                  // 64 timesteps x 64 features
    const int t0 = blockIdx.x * 64;
    const int r  = blockIdx.y * 256 + threadIdx.x;

    const float4* usrc = (const float4*)(u + (size_t)t0 * F_IN);
    float4* udst = (float4*)u_s;
#pragma unroll
    for (int i = 0; i < 4; ++i)
        udst[threadIdx.x + 256 * i] = usrc[threadIdx.x + 256 * i];
    __syncthreads();

    float w[F_IN];
    const float4* wrow = (const float4*)(Winw + (size_t)r * F_IN);
#pragma unroll
    for (int k = 0; k < F_IN / 4; ++k) {
        float4 v = wrow[k];
        w[4*k] = v.x; w[4*k+1] = v.y; w[4*k+2] = v.z; w[4*k+3] = v.w;
    }
    const float bias = Winb[r];

    for (int tt = 0; tt < 64; ++tt) {
        const float4* ur = (const float4*)(u_s + tt * F_IN);  // wave-uniform broadcast
        float acc = bias;
#pragma unroll
        for (int k = 0; k < F_IN / 4; ++k) {
            float4 uv = ur[k];
            acc += w[4*k] * uv.x + w[4*k+1] * uv.y + w[4*k+2] * uv.z + w[4*k+3] * uv.w;
        }
        proj[(size_t)(t0 + tt) * R_DIM + r] = acc;   // coalesced per tt
    }
}

// ---------------- packet publish: 32 B x-slice + epoch, one 64-B line --------
// Relaxed agent-scope stores (bypass stale caches, NO wbl2/inv fences).
// vmcnt(0) between data stores and epoch store orders them at the coherence
// point: a consumer that sees epoch>=t is guaranteed to read fresh data.
__device__ __forceinline__ void publish_slice(unsigned long long* pkt, int slot,
                                              unsigned int epoch,
                                              const float* xnew_lds)
{
    unsigned long long* dst = pkt + (size_t)slot * PKT_U64;
    const unsigned long long* src = (const unsigned long long*)xnew_lds;
#pragma unroll
    for (int i = 0; i < 4; ++i)
        __hip_atomic_store(&dst[i], src[i], __ATOMIC_RELAXED,
                           __HIP_MEMORY_SCOPE_AGENT);
    asm volatile("s_waitcnt vmcnt(0)" ::: "memory");   // data visible before epoch
    __hip_atomic_store((unsigned int*)(dst + 4), epoch, __ATOMIC_RELAXED,
                       __HIP_MEMORY_SCOPE_AGENT);
}

// ---------------- persistent recurrence kernel -------------------------------
// 256 blocks x 256 threads (cooperative). Block owns 8 rows of Wres held in 64
// NAMED scalar floats (no array -> SROA cannot demote to scratch; asm pins
// prevent remat). Rounds 4/6 proved float w[64] goes to scratch regardless of
// pragmas (SROA runs before unrolling): VGPR_Count stuck at 52/56, FETCH 1.5GB.
#define WLOAD(K) \
    float4 wv##K = wrow[K]; \
    float w##K##a = wv##K.x, w##K##b = wv##K.y, w##K##c = wv##K.z, w##K##d = wv##K.w; \
    asm volatile("" : "+v"(w##K##a), "+v"(w##K##b), "+v"(w##K##c), "+v"(w##K##d));

#define WFMA(K) { \
    float4 xv = *(const float4*)(xseg + 4 * K); \
    acc += w##K##a * xv.x + w##K##b * xv.y + w##K##c * xv.z + w##K##d * xv.w; }

__global__ __launch_bounds__(256, 1) void esn_recur_kernel(
    const float* __restrict__ Wres, float* __restrict__ out,
    unsigned long long* pkt)
{
    const int tid   = threadIdx.x;
    const int row_l = tid >> 5;          // 0..7  : local row
    const int seg   = tid & 31;          // 0..31 : 64-col segment of that row
    const int bid   = blockIdx.x;
    const int r     = bid * ROWS_PER_BLK + row_l;

    // W fragment: W[r][seg*64 .. seg*64+63] -> 64 named VGPR floats
    const float4* wrow = (const float4*)(Wres + (size_t)r * R_DIM + seg * 64);
    WLOAD(0)  WLOAD(1)  WLOAD(2)  WLOAD(3)
    WLOAD(4)  WLOAD(5)  WLOAD(6)  WLOAD(7)
    WLOAD(8)  WLOAD(9)  WLOAD(10) WLOAD(11)
    WLOAD(12) WLOAD(13) WLOAD(14) WLOAD(15)

    __shared__ float xs[R_DIM + (R_DIM / 64) * 4];     // 8704 B, padded
    __shared__ __align__(16) float xnew[ROWS_PER_BLK]; // block's 8 new x values

    // step 0: x0 = tanh(proj[0]) (no leak, no Wres term)
    float xcur = 0.f;
    if (seg == 0) {
        xcur = fast_tanh(out[r]);
        out[r] = xcur;
        xnew[row_l] = xcur;
    }
    __syncthreads();
    if (tid == 0) publish_slice(pkt, bid, 1u, xnew);   // parity 0, epoch 1

    for (int t = 1; t < T_STEPS; ++t) {
        // prefetch proj[t][r] before the wait (own row, written only by proj kernel)
        float p = 0.f;
        if (seg == 0) p = out[(size_t)t * R_DIM + r];

        const int par = (t - 1) & 1;
        // ---- 1) arrival: thread tid waits on block tid's packet epoch ----
        {
            const unsigned int* ep = (const unsigned int*)
                (pkt + (size_t)(par * G_BLK + tid) * PKT_U64 + 4);
            while (__hip_atomic_load(ep, __ATOMIC_RELAXED,
                                     __HIP_MEMORY_SCOPE_AGENT) < (unsigned int)t)
                __builtin_amdgcn_s_sleep(1);
        }
        __syncthreads();   // all 256 packets of step t-1 have arrived (L3-hot)

        // ---- 2) redistributed gather: ull x-index u = tid + 256*i lives in
        //      packet u>>2, word u&3. Coalesced global reads; LDS b64 writes at
        //      float-stride 2 -> 2-way banking (free, m136). ----
        const unsigned long long* base = pkt + (size_t)par * G_BLK * PKT_U64;
#pragma unroll
        for (int i = 0; i < 4; ++i) {
            int u = tid + 256 * i;
            unsigned long long v = __hip_atomic_load(
                &base[(size_t)(u >> 2) * PKT_U64 + (u & 3)],
                __ATOMIC_RELAXED, __HIP_MEMORY_SCOPE_AGENT);
            *(unsigned long long*)&xs[xidx(2 * u)] = v;
        }
        __syncthreads();

        // ---- 3) 64 FMAs against register-resident W ----
        const float* xseg = xs + xidx(seg * 64);
        float acc = 0.f;
        WFMA(0)  WFMA(1)  WFMA(2)  WFMA(3)
        WFMA(4)  WFMA(5)  WFMA(6)  WFMA(7)
        WFMA(8)  WFMA(9)  WFMA(10) WFMA(11)
        WFMA(12) WFMA(13) WFMA(14) WFMA(15)

        // reduce 32 segments -> row dot (stays within each 32-lane half)
        acc += __shfl_xor(acc, 16);
        acc += __shfl_xor(acc, 8);
        acc += __shfl_xor(acc, 4);
        acc += __shfl_xor(acc, 2);
        acc += __shfl_xor(acc, 1);

        if (seg == 0) {
            float xi = fast_tanh(p + acc);
            float xn = (1.f - LR) * xcur + LR * xi;
            xcur = xn;                                  // row state stays in-register
            out[(size_t)t * R_DIM + r] = xn;            // fire-and-forget
            xnew[row_l] = xn;
        }
        __syncthreads();   // xnew complete; xs reads done before next overwrite
        if (tid == 0)
            publish_slice(pkt, (t & 1) * G_BLK + bid, (unsigned int)(t + 1), xnew);
    }
}

extern "C" void kernel_launch(void* const* d_in, const int* in_sizes, int n_in,
                              void* d_out, int out_size, void* d_ws, size_t ws_size,
                              hipStream_t stream)
{
    const float* u    = (const float*)d_in[0];   // [8192, 64]
    const float* Winw = (const float*)d_in[1];   // [2048, 64]
    const float* Winb = (const float*)d_in[2];   // [2048]
    const float* Wres = (const float*)d_in[3];   // [2048, 2048]
    float* out = (float*)d_out;                  // [8192, 2048]

    unsigned long long* pkt = (unsigned long long*)d_ws;  // [2][256] 64-B packets
    const size_t pkt_bytes = 2 * G_BLK * PKT_U64 * sizeof(unsigned long long); // 32 KB

    hipMemsetAsync(pkt, 0, pkt_bytes, stream);   // epochs=0 (ws is 0xAA-poisoned)

    dim3 pgrid(T_STEPS / 64, R_DIM / 256);
    esn_proj_kernel<<<pgrid, 256, 0, stream>>>(u, Winw, Winb, out);

    // Cooperative launch: co-residency of all 256 blocks guaranteed -> the
    // packet barrier cannot deadlock.
    const float* WresArg = Wres;
    float* outArg = out;
    unsigned long long* pktArg = pkt;
    void* args[] = { (void*)&WresArg, (void*)&outArg, (void*)&pktArg };
    hipLaunchCooperativeKernel((void*)esn_recur_kernel, dim3(G_BLK), dim3(256),
                               args, 0, stream);
}

// Round 11
// 29446.240 us; speedup vs baseline: 1.4268x; 1.4268x over previous
//
#include <hip/hip_runtime.h>

#define T_STEPS 8192
#define F_IN 64
#define R_DIM 2048
#define G_BLK 256
#define ROWS_PER_BLK 8     // R_DIM / G_BLK
#define WPAD 2560          // padded row: P(c) = c + 16*(c>>6), 2048 -> 2560 floats

// tanh via v_exp_f32: 1 - 2/(e^{2y}+1). e=inf -> 1, e=0 -> -1 (no NaN), ~1e-6 rel err.
__device__ __forceinline__ float fast_tanh(float y) {
    float e = __expf(2.f * y);
    return 1.f - 2.f / (e + 1.f);
}

// ---------------- proj = u_in @ Win^T + b  (one-time, written into d_out) ----
__global__ __launch_bounds__(256) void esn_proj_kernel(
    const float* __restrict__ u, const float* __restrict__ Winw,
    const float* __restrict__ Winb, float* __restrict__ proj)
{
    __shared__ float u_s[64 * F_IN];                  // 64 timesteps x 64 features
    const int t0 = blockIdx.x * 64;
    const int r  = blockIdx.y * 256 + threadIdx.x;

    const float4* usrc = (const float4*)(u + (size_t)t0 * F_IN);
    float4* udst = (float4*)u_s;
#pragma unroll
    for (int i = 0; i < 4; ++i)
        udst[threadIdx.x + 256 * i] = usrc[threadIdx.x + 256 * i];
    __syncthreads();

    float w[F_IN];
    const float4* wrow = (const float4*)(Winw + (size_t)r * F_IN);
#pragma unroll
    for (int k = 0; k < F_IN / 4; ++k) {
        float4 v = wrow[k];
        w[4*k] = v.x; w[4*k+1] = v.y; w[4*k+2] = v.z; w[4*k+3] = v.w;
    }
    const float bias = Winb[r];

    for (int tt = 0; tt < 64; ++tt) {
        const float4* ur = (const float4*)(u_s + tt * F_IN);  // wave-uniform broadcast
        float acc = bias;
#pragma unroll
        for (int k = 0; k < F_IN / 4; ++k) {
            float4 uv = ur[k];
            acc += w[4*k] * uv.x + w[4*k+1] * uv.y + w[4*k+2] * uv.z + w[4*k+3] * uv.w;
        }
        proj[(size_t)(t0 + tt) * R_DIM + r] = acc;   // coalesced per tt
    }
}

// ---------------- persistent recurrence kernel -------------------------------
// 256 blocks x 256 threads (cooperative, 1 block/CU). W slice (8 rows, 80 KB
// padded) lives in LDS (guaranteed on-chip; rounds 4/6/9 proved the register
// allocator demotes a 64-float working set to scratch no matter how pinned).
// Cross-block exchange: each x entry is ONE relaxed agent-scope u64
// {epoch<<32 | float bits} — data+flag atomic together, so publish is
// fire-and-forget (no vmcnt, no fence, no thread-0 funnel) and the consumers'
// gather doubles as the poll. Double-buffered by step parity.

// gather macros: vv##I holds packet word tid+256*I; wait until embedded epoch
// >= t, then stage the float into padded LDS. phys(j) = j + 16*(j>>6).
#define GLOAD(I) \
    vv##I = __hip_atomic_load(&bsrc[tid + 256 * I], __ATOMIC_RELAXED, \
                              __HIP_MEMORY_SCOPE_AGENT);
#define GWAIT(I) \
    while ((unsigned)(vv##I >> 32) < ut) { \
        __builtin_amdgcn_s_sleep(1); \
        GLOAD(I) \
    } \
    xs[tid + 256 * I + 16 * ((tid >> 6) + 4 * I)] = \
        __uint_as_float((unsigned)vv##I);

__global__ __launch_bounds__(256, 1) void esn_recur_kernel(
    const float* __restrict__ Wres, float* __restrict__ out,
    unsigned long long* pkt)
{
    const int tid   = threadIdx.x;
    const int row_l = tid >> 5;          // 0..7  : local row
    const int seg   = tid & 31;          // 0..31 : 64-col segment of that row
    const int bid   = blockIdx.x;
    const int r     = bid * ROWS_PER_BLK + row_l;

    __shared__ __align__(16) float Wlds[ROWS_PER_BLK * WPAD];  // 80 KB
    __shared__ __align__(16) float xs[WPAD];                   // 10 KB

    // ---- stage W slice into LDS with pad P(c)=c+16*(c>>6) (once) ----
    for (int row = 0; row < ROWS_PER_BLK; ++row) {
        const float4* src = (const float4*)(Wres + (size_t)(bid * ROWS_PER_BLK + row) * R_DIM);
        float* drow = Wlds + row * WPAD;
#pragma unroll
        for (int ii = 0; ii < 2; ++ii) {
            int c4 = tid + 256 * ii;                 // float4 index 0..511
            float4 v = src[c4];
            *(float4*)&drow[4 * c4 + 16 * (c4 >> 4)] = v;   // 16B-aligned
        }
    }

    // step 0: x0 = tanh(proj[0]) (no leak, no Wres term); publish epoch 1
    float xcur = 0.f;
    if (seg == 0) {
        xcur = fast_tanh(out[r]);
        out[r] = xcur;
        unsigned long long pv =
            (1ull << 32) | (unsigned long long)__float_as_uint(xcur);
        __hip_atomic_store(&pkt[r], pv, __ATOMIC_RELAXED,
                           __HIP_MEMORY_SCOPE_AGENT);
    }

    const int s15 = seg & 15;
    const float* xb = xs + seg * 80;                     // phys base, this seg
    const float* wb = Wlds + row_l * WPAD + seg * 80;

    for (int t = 1; t < T_STEPS; ++t) {
        // prefetch proj[t][r] (own row; written only by proj kernel)
        float p = 0.f;
        if (seg == 0) p = out[(size_t)t * R_DIM + r];

        // ---- gather x_{t-1}: poll+load fused (epoch embedded in each u64) --
        const unsigned long long* bsrc = pkt + ((t - 1) & 1) * R_DIM;
        const unsigned ut = (unsigned)t;
        unsigned long long vv0, vv1, vv2, vv3, vv4, vv5, vv6, vv7;
        GLOAD(0) GLOAD(1) GLOAD(2) GLOAD(3)              // 8 loads in flight
        GLOAD(4) GLOAD(5) GLOAD(6) GLOAD(7)
        GWAIT(0) GWAIT(1) GWAIT(2) GWAIT(3)
        GWAIT(4) GWAIT(5) GWAIT(6) GWAIT(7)
        __syncthreads();                                  // xs complete

        // ---- 64 FMAs: W and x both from LDS, rotated chunks kk=(k+seg)&15 --
        // span(lane) = (4*seg + kk) % 8 -> all 8 b128 bank-spans hit by
        // exactly 8 lanes each: conflict-free at the b128 optimum.
        float acc = 0.f;
#pragma unroll
        for (int k = 0; k < 16; ++k) {
            int off = (((k + s15) & 15) << 2);            // float offset 0..60
            float4 wv = *(const float4*)(wb + off);
            float4 xv = *(const float4*)(xb + off);
            acc += wv.x * xv.x + wv.y * xv.y + wv.z * xv.z + wv.w * xv.w;
        }
        // reduce 32 segments -> row dot (stays within each 32-lane half)
        acc += __shfl_xor(acc, 16);
        acc += __shfl_xor(acc, 8);
        acc += __shfl_xor(acc, 4);
        acc += __shfl_xor(acc, 2);
        acc += __shfl_xor(acc, 1);

        if (seg == 0) {
            float xi = fast_tanh(p + acc);
            float xn = 0.1f * xcur + 0.9f * xi;
            xcur = xn;
            out[(size_t)t * R_DIM + r] = xn;              // fire-and-forget
            unsigned long long pv =
                ((unsigned long long)(unsigned)(t + 1) << 32) |
                (unsigned long long)__float_as_uint(xn);
            __hip_atomic_store(&pkt[(t & 1) * R_DIM + r], pv,
                               __ATOMIC_RELAXED, __HIP_MEMORY_SCOPE_AGENT);
        }
        __syncthreads();   // all xs reads done before next gather overwrites;
                           // also completes the gather-all -> publish induction
                           // that makes the 2-buffer overwrite race-free
    }
}

extern "C" void kernel_launch(void* const* d_in, const int* in_sizes, int n_in,
                              void* d_out, int out_size, void* d_ws, size_t ws_size,
                              hipStream_t stream)
{
    const float* u    = (const float*)d_in[0];   // [8192, 64]
    const float* Winw = (const float*)d_in[1];   // [2048, 64]
    const float* Winb = (const float*)d_in[2];   // [2048]
    const float* Wres = (const float*)d_in[3];   // [2048, 2048]
    float* out = (float*)d_out;                  // [8192, 2048]

    unsigned long long* pkt = (unsigned long long*)d_ws;  // [2][2048] u64 = 32 KB
    const size_t pkt_bytes = 2 * R_DIM * sizeof(unsigned long long);

    hipMemsetAsync(pkt, 0, pkt_bytes, stream);   // epochs=0 (ws is 0xAA-poisoned)

    dim3 pgrid(T_STEPS / 64, R_DIM / 256);
    esn_proj_kernel<<<pgrid, 256, 0, stream>>>(u, Winw, Winb, out);

    // Cooperative launch: co-residency of all 256 blocks guaranteed -> the
    // embedded-epoch exchange cannot deadlock.
    const float* WresArg = Wres;
    float* outArg = out;
    unsigned long long* pktArg = pkt;
    void* args[] = { (void*)&WresArg, (void*)&outArg, (void*)&pktArg };
    hipLaunchCooperativeKernel((void*)esn_recur_kernel, dim3(G_BLK), dim3(256),
                               args, 0, stream);
}

// Round 13
// 13619.263 us; speedup vs baseline: 3.0849x; 2.1621x over previous
//
#include <hip/hip_runtime.h>

#define T_STEPS 8192
#define F_IN 64
#define R_DIM 2048
#define G_BLK 256
#define ROWS_PER_BLK 8     // R_DIM / G_BLK
#define WPAD 2560          // padded row: P(c) = c + 16*(c>>6), 2048 -> 2560 floats

typedef unsigned int u32x4 __attribute__((ext_vector_type(4)));

// tanh via v_exp_f32: 1 - 2/(e^{2y}+1). e=inf -> 1, e=0 -> -1 (no NaN), ~1e-6 rel err.
__device__ __forceinline__ float fast_tanh(float y) {
    float e = __expf(2.f * y);
    return 1.f - 2.f / (e + 1.f);
}

// ---------------- proj = u_in @ Win^T + b  (one-time, written into d_out) ----
__global__ __launch_bounds__(256) void esn_proj_kernel(
    const float* __restrict__ u, const float* __restrict__ Winw,
    const float* __restrict__ Winb, float* __restrict__ proj)
{
    __shared__ float u_s[64 * F_IN];                  // 64 timesteps x 64 features
    const int t0 = blockIdx.x * 64;
    const int r  = blockIdx.y * 256 + threadIdx.x;

    const float4* usrc = (const float4*)(u + (size_t)t0 * F_IN);
    float4* udst = (float4*)u_s;
#pragma unroll
    for (int i = 0; i < 4; ++i)
        udst[threadIdx.x + 256 * i] = usrc[threadIdx.x + 256 * i];
    __syncthreads();

    float w[F_IN];
    const float4* wrow = (const float4*)(Winw + (size_t)r * F_IN);
#pragma unroll
    for (int k = 0; k < F_IN / 4; ++k) {
        float4 v = wrow[k];
        w[4*k] = v.x; w[4*k+1] = v.y; w[4*k+2] = v.z; w[4*k+3] = v.w;
    }
    const float bias = Winb[r];

    for (int tt = 0; tt < 64; ++tt) {
        const float4* ur = (const float4*)(u_s + tt * F_IN);  // wave-uniform broadcast
        float acc = bias;
#pragma unroll
        for (int k = 0; k < F_IN / 4; ++k) {
            float4 uv = ur[k];
            acc += w[4*k] * uv.x + w[4*k+1] * uv.y + w[4*k+2] * uv.z + w[4*k+3] * uv.w;
        }
        proj[(size_t)(t0 + tt) * R_DIM + r] = acc;   // coalesced per tt
    }
}

// ---------------- persistent recurrence kernel -------------------------------
// 256 blocks x 256 threads (cooperative, 1 block/CU). W slice (8 rows, 80 KB
// padded) lives in LDS. Cross-block exchange: each x entry is one u64
// {epoch<<32 | float bits} published with a relaxed agent-scope store
// (fire-and-forget). Gather = WIDE polling: 4x global_load_dwordx4 sc0 sc1
// (L1/L2-bypass, coalesced) issued together + ONE vmcnt(0) per sweep, then all
// 8 embedded epochs checked at once. Round 11's per-word scalar retry chain
// serialized 2-4 L3 round-trips (~3 us/step); a sweep costs exactly one.
__global__ __launch_bounds__(256, 1) void esn_recur_kernel(
    const float* __restrict__ Wres, float* __restrict__ out,
    unsigned long long* pkt)
{
    const int tid   = threadIdx.x;
    const int row_l = tid >> 5;          // 0..7  : local row
    const int seg   = tid & 31;          // 0..31 : 64-col segment of that row
    const int bid   = blockIdx.x;
    const int r     = bid * ROWS_PER_BLK + row_l;

    __shared__ __align__(16) float Wlds[ROWS_PER_BLK * WPAD];  // 80 KB
    __shared__ __align__(16) float xs[WPAD];                   // 10 KB

    // ---- stage W slice into LDS with pad P(c)=c+16*(c>>6) (once) ----
    for (int row = 0; row < ROWS_PER_BLK; ++row) {
        const float4* src = (const float4*)(Wres + (size_t)(bid * ROWS_PER_BLK + row) * R_DIM);
        float* drow = Wlds + row * WPAD;
#pragma unroll
        for (int ii = 0; ii < 2; ++ii) {
            int c4 = tid + 256 * ii;                 // float4 index 0..511
            float4 v = src[c4];
            *(float4*)&drow[4 * c4 + 16 * (c4 >> 4)] = v;   // 16B-aligned
        }
    }

    // step 0: x0 = tanh(proj[0]) (no leak, no Wres term); publish epoch 1
    float xcur = 0.f;
    if (seg == 0) {
        xcur = fast_tanh(out[r]);
        out[r] = xcur;
        unsigned long long pv =
            (1ull << 32) | (unsigned long long)__float_as_uint(xcur);
        __hip_atomic_store(&pkt[r], pv, __ATOMIC_RELAXED,
                           __HIP_MEMORY_SCOPE_AGENT);
    }

    const int s15 = seg & 15;
    const float* xb = xs + seg * 80;                     // phys base, this seg
    const float* wb = Wlds + row_l * WPAD + seg * 80;

    for (int t = 1; t < T_STEPS; ++t) {
        // prefetch proj[t][r] (own row; written only by proj kernel)
        float p = 0.f;
        if (seg == 0) p = out[(size_t)t * R_DIM + r];

        // ---- gather x_{t-1}: wide-sweep polling, one L3 latency per sweep --
        // chunk j covers u64 words 2*(tid+256j) .. +1 (x entries 2c, 2c+1)
        const unsigned long long* bsrc = pkt + ((t - 1) & 1) * R_DIM;
        const unsigned ut = (unsigned)t;
        const unsigned long long* p0 = bsrc + 2 * (tid);
        const unsigned long long* p1 = bsrc + 2 * (tid + 256);
        const unsigned long long* p2 = bsrc + 2 * (tid + 512);
        const unsigned long long* p3 = bsrc + 2 * (tid + 768);
        u32x4 va, vb, vc, vd;     // .x=val0 .y=epoch0 .z=val1 .w=epoch1
        for (;;) {
            asm volatile(
                "global_load_dwordx4 %0, %4, off sc0 sc1\n\t"
                "global_load_dwordx4 %1, %5, off sc0 sc1\n\t"
                "global_load_dwordx4 %2, %6, off sc0 sc1\n\t"
                "global_load_dwordx4 %3, %7, off sc0 sc1\n\t"
                "s_waitcnt vmcnt(0)"
                : "=&v"(va), "=&v"(vb), "=&v"(vc), "=&v"(vd)
                : "v"(p0), "v"(p1), "v"(p2), "v"(p3)
                : "memory");
            bool ok = (va.y >= ut) & (va.w >= ut) & (vb.y >= ut) & (vb.w >= ut) &
                      (vc.y >= ut) & (vc.w >= ut) & (vd.y >= ut) & (vd.w >= ut);
            if (__all(ok)) break;       // wave-uniform; re-reads are idempotent
            __builtin_amdgcn_s_sleep(1);
        }
        // stage to padded LDS: x indices 2c,2c+1 share a 64-group -> one 8B store
        {
            int c0 = 2 * tid;
            *(float2*)&xs[c0 + 16 * (c0 >> 6)] =
                make_float2(__uint_as_float(va.x), __uint_as_float(va.z));
            int c1 = 2 * (tid + 256);
            *(float2*)&xs[c1 + 16 * (c1 >> 6)] =
                make_float2(__uint_as_float(vb.x), __uint_as_float(vb.z));
            int c2 = 2 * (tid + 512);
            *(float2*)&xs[c2 + 16 * (c2 >> 6)] =
                make_float2(__uint_as_float(vc.x), __uint_as_float(vc.z));
            int c3 = 2 * (tid + 768);
            *(float2*)&xs[c3 + 16 * (c3 >> 6)] =
                make_float2(__uint_as_float(vd.x), __uint_as_float(vd.z));
        }
        __syncthreads();                                  // xs complete

        // ---- 64 FMAs: W and x both from LDS, rotated chunks kk=(k+seg)&15 --
        // span(lane) = (4*seg + kk) % 8 -> all 8 b128 bank-spans hit by
        // exactly 8 lanes each: conflict-free (round 11: SQ_LDS_BANK_CONFLICT=0).
        float acc = 0.f;
#pragma unroll
        for (int k = 0; k < 16; ++k) {
            int off = (((k + s15) & 15) << 2);            // float offset 0..60
            float4 wv = *(const float4*)(wb + off);
            float4 xv = *(const float4*)(xb + off);
            acc += wv.x * xv.x + wv.y * xv.y + wv.z * xv.z + wv.w * xv.w;
        }
        // reduce 32 segments -> row dot (stays within each 32-lane half)
        acc += __shfl_xor(acc, 16);
        acc += __shfl_xor(acc, 8);
        acc += __shfl_xor(acc, 4);
        acc += __shfl_xor(acc, 2);
        acc += __shfl_xor(acc, 1);

        if (seg == 0) {
            float xi = fast_tanh(p + acc);
            float xn = 0.1f * xcur + 0.9f * xi;
            xcur = xn;
            out[(size_t)t * R_DIM + r] = xn;              // fire-and-forget
            unsigned long long pv =
                ((unsigned long long)(unsigned)(t + 1) << 32) |
                (unsigned long long)__float_as_uint(xn);
            __hip_atomic_store(&pkt[(t & 1) * R_DIM + r], pv,
                               __ATOMIC_RELAXED, __HIP_MEMORY_SCOPE_AGENT);
        }
        __syncthreads();   // all xs reads done before next gather overwrites;
                           // completes the gather-all -> publish induction that
                           // makes the 2-buffer overwrite race-free
    }
}

extern "C" void kernel_launch(void* const* d_in, const int* in_sizes, int n_in,
                              void* d_out, int out_size, void* d_ws, size_t ws_size,
                              hipStream_t stream)
{
    const float* u    = (const float*)d_in[0];   // [8192, 64]
    const float* Winw = (const float*)d_in[1];   // [2048, 64]
    const float* Winb = (const float*)d_in[2];   // [2048]
    const float* Wres = (const float*)d_in[3];   // [2048, 2048]
    float* out = (float*)d_out;                  // [8192, 2048]

    unsigned long long* pkt = (unsigned long long*)d_ws;  // [2][2048] u64 = 32 KB
    const size_t pkt_bytes = 2 * R_DIM * sizeof(unsigned long long);

    hipMemsetAsync(pkt, 0, pkt_bytes, stream);   // epochs=0 (ws is 0xAA-poisoned)

    dim3 pgrid(T_STEPS / 64, R_DIM / 256);
    esn_proj_kernel<<<pgrid, 256, 0, stream>>>(u, Winw, Winb, out);

    // Cooperative launch: co-residency of all 256 blocks guaranteed -> the
    // embedded-epoch exchange cannot deadlock.
    const float* WresArg = Wres;
    float* outArg = out;
    unsigned long long* pktArg = pkt;
    void* args[] = { (void*)&WresArg, (void*)&outArg, (void*)&pktArg };
    hipLaunchCooperativeKernel((void*)esn_recur_kernel, dim3(G_BLK), dim3(256),
                               args, 0, stream);
}

// Round 14
// 13599.025 us; speedup vs baseline: 3.0895x; 1.0015x over previous
//
#include <hip/hip_runtime.h>

#define T_STEPS 8192
#define F_IN 64
#define R_DIM 2048
#define G_BLK 256
#define ROWS_PER_BLK 8     // R_DIM / G_BLK
#define WPAD 2560          // padded row: P(c) = c + 16*(c>>6), 2048 -> 2560 floats

typedef unsigned int u32x4 __attribute__((ext_vector_type(4)));

// tanh via v_exp_f32: 1 - 2/(e^{2y}+1). e=inf -> 1, e=0 -> -1 (no NaN), ~1e-6 rel err.
__device__ __forceinline__ float fast_tanh(float y) {
    float e = __expf(2.f * y);
    return 1.f - 2.f / (e + 1.f);
}

// ---------------- proj = u_in @ Win^T + b  (one-time, written into d_out) ----
__global__ __launch_bounds__(256) void esn_proj_kernel(
    const float* __restrict__ u, const float* __restrict__ Winw,
    const float* __restrict__ Winb, float* __restrict__ proj)
{
    __shared__ float u_s[64 * F_IN];                  // 64 timesteps x 64 features
    const int t0 = blockIdx.x * 64;
    const int r  = blockIdx.y * 256 + threadIdx.x;

    const float4* usrc = (const float4*)(u + (size_t)t0 * F_IN);
    float4* udst = (float4*)u_s;
#pragma unroll
    for (int i = 0; i < 4; ++i)
        udst[threadIdx.x + 256 * i] = usrc[threadIdx.x + 256 * i];
    __syncthreads();

    float w[F_IN];
    const float4* wrow = (const float4*)(Winw + (size_t)r * F_IN);
#pragma unroll
    for (int k = 0; k < F_IN / 4; ++k) {
        float4 v = wrow[k];
        w[4*k] = v.x; w[4*k+1] = v.y; w[4*k+2] = v.z; w[4*k+3] = v.w;
    }
    const float bias = Winb[r];

    for (int tt = 0; tt < 64; ++tt) {
        const float4* ur = (const float4*)(u_s + tt * F_IN);  // wave-uniform broadcast
        float acc = bias;
#pragma unroll
        for (int k = 0; k < F_IN / 4; ++k) {
            float4 uv = ur[k];
            acc += w[4*k] * uv.x + w[4*k+1] * uv.y + w[4*k+2] * uv.z + w[4*k+3] * uv.w;
        }
        proj[(size_t)(t0 + tt) * R_DIM + r] = acc;   // coalesced per tt
    }
}

// ---------------- persistent recurrence kernel -------------------------------
// 256 blocks x 256 threads (cooperative, 1 block/CU). W slice (8 rows, 80 KB
// padded) lives in LDS. Exchange: each x entry is one u64 {epoch<<32|bits}
// relaxed agent-scope store; gather = wide-sweep poll (4x dwordx4 sc0 sc1 +
// one vmcnt(0) per sweep). ROUND-14 CHANGE: barrier restructure.
//  - Trailing __syncthreads REMOVED: redundant. Each wave's seg==0 lanes
//    publish only after the wave's xs ds_reads are consumed (program order +
//    data dep); a sweep for t+1 passes only when ALL waves of ALL blocks have
//    published t+1 -> no thread can overwrite xs while any thread reads it.
//  - Leading barrier softened to raw {s_waitcnt lgkmcnt(0); s_barrier}: no
//    vmcnt(0) drain, so the publish-store ACK overlaps the next poll
//    (max instead of sum) and the proj prefetch isn't drained early.
__global__ __launch_bounds__(256, 1) void esn_recur_kernel(
    const float* __restrict__ Wres, float* __restrict__ out,
    unsigned long long* pkt)
{
    const int tid   = threadIdx.x;
    const int row_l = tid >> 5;          // 0..7  : local row
    const int seg   = tid & 31;          // 0..31 : 64-col segment of that row
    const int bid   = blockIdx.x;
    const int r     = bid * ROWS_PER_BLK + row_l;

    __shared__ __align__(16) float Wlds[ROWS_PER_BLK * WPAD];  // 80 KB
    __shared__ __align__(16) float xs[WPAD];                   // 10 KB

    // ---- stage W slice into LDS with pad P(c)=c+16*(c>>6) (once) ----
    for (int row = 0; row < ROWS_PER_BLK; ++row) {
        const float4* src = (const float4*)(Wres + (size_t)(bid * ROWS_PER_BLK + row) * R_DIM);
        float* drow = Wlds + row * WPAD;
#pragma unroll
        for (int ii = 0; ii < 2; ++ii) {
            int c4 = tid + 256 * ii;                 // float4 index 0..511
            float4 v = src[c4];
            *(float4*)&drow[4 * c4 + 16 * (c4 >> 4)] = v;   // 16B-aligned
        }
    }

    // step 0: x0 = tanh(proj[0]) (no leak, no Wres term); publish epoch 1
    float xcur = 0.f;
    if (seg == 0) {
        xcur = fast_tanh(out[r]);
        out[r] = xcur;
        unsigned long long pv =
            (1ull << 32) | (unsigned long long)__float_as_uint(xcur);
        __hip_atomic_store(&pkt[r], pv, __ATOMIC_RELAXED,
                           __HIP_MEMORY_SCOPE_AGENT);
    }

    const int s15 = seg & 15;
    const float* xb = xs + seg * 80;                     // phys base, this seg
    const float* wb = Wlds + row_l * WPAD + seg * 80;

    for (int t = 1; t < T_STEPS; ++t) {
        // prefetch proj[t][r] (own row; written only by proj kernel)
        float p = 0.f;
        if (seg == 0) p = out[(size_t)t * R_DIM + r];

        // ---- gather x_{t-1}: wide-sweep polling, one L3 latency per sweep --
        const unsigned long long* bsrc = pkt + ((t - 1) & 1) * R_DIM;
        const unsigned ut = (unsigned)t;
        const unsigned long long* p0 = bsrc + 2 * (tid);
        const unsigned long long* p1 = bsrc + 2 * (tid + 256);
        const unsigned long long* p2 = bsrc + 2 * (tid + 512);
        const unsigned long long* p3 = bsrc + 2 * (tid + 768);
        u32x4 va, vb, vc, vd;     // .x=val0 .y=epoch0 .z=val1 .w=epoch1
        for (;;) {
            asm volatile(
                "global_load_dwordx4 %0, %4, off sc0 sc1\n\t"
                "global_load_dwordx4 %1, %5, off sc0 sc1\n\t"
                "global_load_dwordx4 %2, %6, off sc0 sc1\n\t"
                "global_load_dwordx4 %3, %7, off sc0 sc1\n\t"
                "s_waitcnt vmcnt(0)"
                : "=&v"(va), "=&v"(vb), "=&v"(vc), "=&v"(vd)
                : "v"(p0), "v"(p1), "v"(p2), "v"(p3)
                : "memory");
            bool ok = (va.y >= ut) & (va.w >= ut) & (vb.y >= ut) & (vb.w >= ut) &
                      (vc.y >= ut) & (vc.w >= ut) & (vd.y >= ut) & (vd.w >= ut);
            if (__all(ok)) break;       // wave-uniform; re-reads are idempotent
            __builtin_amdgcn_s_sleep(1);
        }
        // stage to padded LDS: x indices 2c,2c+1 share a 64-group -> one 8B store
        {
            int c0 = 2 * tid;
            *(float2*)&xs[c0 + 16 * (c0 >> 6)] =
                make_float2(__uint_as_float(va.x), __uint_as_float(va.z));
            int c1 = 2 * (tid + 256);
            *(float2*)&xs[c1 + 16 * (c1 >> 6)] =
                make_float2(__uint_as_float(vb.x), __uint_as_float(vb.z));
            int c2 = 2 * (tid + 512);
            *(float2*)&xs[c2 + 16 * (c2 >> 6)] =
                make_float2(__uint_as_float(vc.x), __uint_as_float(vc.z));
            int c3 = 2 * (tid + 768);
            *(float2*)&xs[c3 + 16 * (c3 >> 6)] =
                make_float2(__uint_as_float(vd.x), __uint_as_float(vd.z));
        }
        // raw barrier: LDS ordering only (no vmcnt drain -> publish ack and
        // proj prefetch stay in flight). "memory" clobber pins ds ops.
        asm volatile("s_waitcnt lgkmcnt(0)\n\ts_barrier" ::: "memory");

        // ---- 64 FMAs: W and x both from LDS, rotated chunks kk=(k+seg)&15 --
        // conflict-free (round 11/13: SQ_LDS_BANK_CONFLICT = 0).
        float acc = 0.f;
#pragma unroll
        for (int k = 0; k < 16; ++k) {
            int off = (((k + s15) & 15) << 2);            // float offset 0..60
            float4 wv = *(const float4*)(wb + off);
            float4 xv = *(const float4*)(xb + off);
            acc += wv.x * xv.x + wv.y * xv.y + wv.z * xv.z + wv.w * xv.w;
        }
        // reduce 32 segments -> row dot (stays within each 32-lane half)
        acc += __shfl_xor(acc, 16);
        acc += __shfl_xor(acc, 8);
        acc += __shfl_xor(acc, 4);
        acc += __shfl_xor(acc, 2);
        acc += __shfl_xor(acc, 1);

        if (seg == 0) {
            float xi = fast_tanh(p + acc);
            float xn = 0.1f * xcur + 0.9f * xi;
            xcur = xn;
            out[(size_t)t * R_DIM + r] = xn;              // fire-and-forget
            unsigned long long pv =
                ((unsigned long long)(unsigned)(t + 1) << 32) |
                (unsigned long long)__float_as_uint(xn);
            __hip_atomic_store(&pkt[(t & 1) * R_DIM + r], pv,
                               __ATOMIC_RELAXED, __HIP_MEMORY_SCOPE_AGENT);
        }
        // NO trailing barrier: epoch induction makes it redundant (see header).
    }
}

extern "C" void kernel_launch(void* const* d_in, const int* in_sizes, int n_in,
                              void* d_out, int out_size, void* d_ws, size_t ws_size,
                              hipStream_t stream)
{
    const float* u    = (const float*)d_in[0];   // [8192, 64]
    const float* Winw = (const float*)d_in[1];   // [2048, 64]
    const float* Winb = (const float*)d_in[2];   // [2048]
    const float* Wres = (const float*)d_in[3];   // [2048, 2048]
    float* out = (float*)d_out;                  // [8192, 2048]

    unsigned long long* pkt = (unsigned long long*)d_ws;  // [2][2048] u64 = 32 KB
    const size_t pkt_bytes = 2 * R_DIM * sizeof(unsigned long long);

    hipMemsetAsync(pkt, 0, pkt_bytes, stream);   // epochs=0 (ws is 0xAA-poisoned)

    dim3 pgrid(T_STEPS / 64, R_DIM / 256);
    esn_proj_kernel<<<pgrid, 256, 0, stream>>>(u, Winw, Winb, out);

    // Cooperative launch: co-residency of all 256 blocks guaranteed -> the
    // embedded-epoch exchange cannot deadlock.
    const float* WresArg = Wres;
    float* outArg = out;
    unsigned long long* pktArg = pkt;
    void* args[] = { (void*)&WresArg, (void*)&outArg, (void*)&pktArg };
    hipLaunchCooperativeKernel((void*)esn_recur_kernel, dim3(G_BLK), dim3(256),
                               args, 0, stream);
}